// Round 2
// baseline (755.347 us; speedup 1.0000x reference)
//
#include <hip/hip_runtime.h>
#include <hip/hip_bf16.h>
#include <stdint.h>

#define NN 4096
#define DD 256
#define RR 8

__device__ __forceinline__ float wave_sum(float v) {
#pragma unroll
    for (int off = 32; off > 0; off >>= 1) v += __shfl_down(v, off, 64);
    return v;
}

// blocks [0, 8192): A row-sums + diagonals, 1 wave per (r,i) row; g = r*4096 + i
// block 8192: w[r] = wrel[r] * softmax(LN(x @ W_q + b_q) @ rels)[r] at the node row
__global__ __launch_bounds__(256) void scan_kernel(
    const float* __restrict__ A,
    const float* __restrict__ inputs_embeds,
    const int* __restrict__ token_index,
    const int* __restrict__ node_index,
    const float* __restrict__ rels,
    const float* __restrict__ wrel,
    const float* __restrict__ W_q,
    const float* __restrict__ b_q,
    float* __restrict__ ws_w,
    float* __restrict__ ws_rowsum,
    float* __restrict__ ws_diag)
{
    const int bid = blockIdx.x;
    const int tid = threadIdx.x;

    if (bid < 8192) {
        // ---- A scan: each wave reduces one 4096-float row (16 KB) ----
        const int wid = tid >> 6, lane = tid & 63;
        const int g = bid * 4 + wid;                 // g in [0, 32768)
        const size_t base = (size_t)g * NN;
        const float4* rowp = (const float4*)(A + base);
        float s = 0.f;
#pragma unroll
        for (int t = 0; t < 16; ++t) {
            float4 c = rowp[t * 64 + lane];
            s += (c.x + c.y) + (c.z + c.w);
        }
        s = wave_sum(s);
        if (lane == 0) {
            ws_rowsum[g] = s;
            ws_diag[g]   = A[base + (g & (NN - 1))];  // A[r][i][i]
        }
    } else {
        // ---- relation weights w[0..7] (single block) ----
        __shared__ float xs[DD];
        __shared__ float qs[DD];
        __shared__ float red[4];
        __shared__ float lg[RR];
        const int ni = node_index[0];
        const int ti = token_index[ni];
        xs[tid] = inputs_embeds[(size_t)ti * DD + tid];
        __syncthreads();
        float q = b_q[tid];
        for (int k = 0; k < DD; ++k) q += xs[k] * W_q[k * DD + tid];
        // LayerNorm over DD
        float v = wave_sum(q);
        if ((tid & 63) == 0) red[tid >> 6] = v;
        __syncthreads();
        float mean = (red[0] + red[1] + red[2] + red[3]) * (1.f / DD);
        __syncthreads();
        float c = q - mean;
        v = wave_sum(c * c);
        if ((tid & 63) == 0) red[tid >> 6] = v;
        __syncthreads();
        float var = (red[0] + red[1] + red[2] + red[3]) * (1.f / DD);
        float qn = c * rsqrtf(var + 1e-5f);
        qs[tid] = qn;
        __syncthreads();
        if (tid < RR) {
            float l = 0.f;
            for (int d = 0; d < DD; ++d) l += qs[d] * rels[d * RR + tid];
            lg[tid] = l;
        }
        __syncthreads();
        if (tid == 0) {
            float m = lg[0];
            for (int r = 1; r < RR; ++r) m = fmaxf(m, lg[r]);
            float s = 0.f, ex[RR];
            for (int r = 0; r < RR; ++r) { ex[r] = expf(lg[r] - m); s += ex[r]; }
            for (int r = 0; r < RR; ++r) ws_w[r] = wrel[r] * ex[r] / s;
        }
    }
}

// 512 blocks x 8 rows each:
//   EW[i,:] = edges[i,:] @ W_v          (fused, W_v via L2, amortized 8x)
//   scale_i = tprev[i,i] * (sum_r w_r diagA[r,i]) / (sum_r w_r rowsum[r,i])
//   out[i,:] = LN( edges[node,:] + scale_i * EW[i,:] + b_v )
__global__ __launch_bounds__(256) void fuse_kernel(
    const float* __restrict__ edges,
    const float* __restrict__ W_v,
    const float* __restrict__ b_v,
    const float* __restrict__ tprev,
    const int* __restrict__ node_index,
    const float* __restrict__ ws_w,
    const float* __restrict__ ws_rowsum,
    const float* __restrict__ ws_diag,
    float* __restrict__ out)
{
    const int tid = threadIdx.x;
    const int i0  = blockIdx.x * 8;
    __shared__ float e[8][DD];     // 8 KB
    __shared__ float scl[8];
    __shared__ float red[4];

    const int ni = node_index[0];
#pragma unroll
    for (int r = 0; r < 8; ++r)
        e[r][tid] = edges[(size_t)(i0 + r) * DD + tid];
    if (tid < 8) {
        const int i = i0 + tid;
        float deg = 0.f, dia = 0.f;
#pragma unroll
        for (int r = 0; r < RR; ++r) {
            float wr = ws_w[r];
            deg += wr * ws_rowsum[r * NN + i];
            dia += wr * ws_diag[r * NN + i];
        }
        scl[tid] = tprev[(size_t)i * NN + i] * dia / deg;
    }
    __syncthreads();

    float acc[8] = {0.f, 0.f, 0.f, 0.f, 0.f, 0.f, 0.f, 0.f};
#pragma unroll 4
    for (int k = 0; k < DD; ++k) {
        float wv = W_v[k * DD + tid];      // coalesced; L2-resident (256 KB)
#pragma unroll
        for (int r = 0; r < 8; ++r) acc[r] += e[r][k] * wv;  // LDS broadcast
    }

    const float node_e = edges[(size_t)ni * DD + tid];
    const float bv = b_v[tid];

    for (int r = 0; r < 8; ++r) {
        float vlm = node_e + scl[r] * acc[r] + bv;
        float v = wave_sum(vlm);
        if ((tid & 63) == 0) red[tid >> 6] = v;
        __syncthreads();
        float mean = (red[0] + red[1] + red[2] + red[3]) * (1.f / DD);
        __syncthreads();
        float c = vlm - mean;
        v = wave_sum(c * c);
        if ((tid & 63) == 0) red[tid >> 6] = v;
        __syncthreads();
        float var = (red[0] + red[1] + red[2] + red[3]) * (1.f / DD);
        out[(size_t)(i0 + r) * DD + tid] = c * rsqrtf(var + 1e-5f);
        __syncthreads();   // red reused next iteration
    }
}

extern "C" void kernel_launch(void* const* d_in, const int* in_sizes, int n_in,
                              void* d_out, int out_size, void* d_ws, size_t ws_size,
                              hipStream_t stream) {
    const float* inputs_embeds = (const float*)d_in[0];
    const int*   token_index   = (const int*)d_in[1];
    const int*   node_index    = (const int*)d_in[2];
    const float* edges         = (const float*)d_in[3];
    const float* A             = (const float*)d_in[4];
    const float* rels          = (const float*)d_in[5];
    const float* wrel          = (const float*)d_in[6];
    const float* W_q           = (const float*)d_in[7];
    const float* b_q           = (const float*)d_in[8];
    const float* W_v           = (const float*)d_in[9];
    const float* b_v           = (const float*)d_in[10];
    const float* tprev         = (const float*)d_in[11];

    float* ws        = (float*)d_ws;
    float* ws_w      = ws;                 // 16 floats (8 used)
    float* ws_rowsum = ws + 16;            // 32768 floats
    float* ws_diag   = ws + 16 + 32768;    // 32768 floats   (total ~262 KB)

    scan_kernel<<<8192 + 1, 256, 0, stream>>>(
        A, inputs_embeds, token_index, node_index, rels, wrel, W_q, b_q,
        ws_w, ws_rowsum, ws_diag);

    fuse_kernel<<<NN / 8, 256, 0, stream>>>(
        edges, W_v, b_v, tprev, node_index, ws_w, ws_rowsum, ws_diag,
        (float*)d_out);
}